// Round 1
// baseline (959.266 us; speedup 1.0000x reference)
//
#include <hip/hip_runtime.h>
#include <cstdint>

// ---------------- problem constants ----------------
#define LVLPOS 75240          // 10*66*114 flat padded positions per level
#define GUARD  256            // zero guard positions before/after imgP data
#define NPART  16             // stats partial copies (atomic contention spread)

using f32x4  = __attribute__((ext_vector_type(4))) float;
using bf16x8 = __attribute__((ext_vector_type(8))) __bf16;

static __device__ __forceinline__ unsigned short f2bf(float f) {
  unsigned int u = __float_as_uint(f);
  u += 0x7fffu + ((u >> 16) & 1u);     // round-to-nearest-even
  return (unsigned short)(u >> 16);
}
static __device__ __forceinline__ float bflo(uint32_t d) { return __uint_as_float(d << 16); }
static __device__ __forceinline__ float bfhi(uint32_t d) { return __uint_as_float(d & 0xffff0000u); }

// ---------------- ws layout (bytes) ----------------
// wf     : [3][ck64:4][tap:9][frag 8192] bf16 (fragment-major folded W)  1,769,472
// bias   : [128] f32                                                           512
// pts_wb : [128][128] bf16, fragment-major                                  32,768
// statsP : [16][512] f32 partials                                           32,768
// fdat   : [75264][128] bf16 (level-summed conv output, padded layout)  19,267,584
// imgP   : [(256+3*75240+256)][256] bf16 flat padded NHWC               115,830,784
// img_raw/pts_raw (each 33,554,432) ALIAS imgP (imgP dead after k_conv)
#define OFF_WF     ((size_t)0)
#define OFF_BIAS   ((size_t)1769472)
#define OFF_PTSWB  ((size_t)1769984)
#define OFF_STATSP ((size_t)1802752)
#define OFF_FDAT   ((size_t)1835520)
#define OFF_IMGP   ((size_t)21103104)
#define OFF_IRAW   OFF_IMGP
#define OFF_PRAW   (OFF_IMGP + (size_t)33554432)

// =====================================================================
// setup: fold weights (432), zero imgP pads (62), bias+pts prepack (65),
// zero statsP (8).  grid 567.
// =====================================================================
__global__ __launch_bounds__(256) void k_setup(const float* __restrict__ img_w,
                                               const float* __restrict__ conv_w,
                                               const float* __restrict__ conv_b,
                                               const float* __restrict__ pts_w,
                                               unsigned short* __restrict__ wf,
                                               float* __restrict__ bias,
                                               unsigned short* __restrict__ pts_wb,
                                               unsigned short* __restrict__ imgP,
                                               float* __restrict__ statsP) {
  __shared__ float smem[12544];                 // iw 64x130 + cw 128x33 = 50176 B
  const int b = blockIdx.x, t = threadIdx.x;
  if (b < 432) {
    // fold: wf[l][ck64][tap][frag]; block = (l, tap, ck32, o-half)
    int z = b >> 1, oh = b & 1;
    int l = z / 72, r = z % 72, tap = r / 8, ckk = r % 8;
    float* iw = smem;                           // [64 o][130]
    float* cw = smem + 8320;                    // [128 mid][33]
    for (int v = t; v < 2048; v += 256) {
      int o = v >> 5, seg = v & 31;
      float4 f = *(const float4*)(img_w + (size_t)(oh * 64 + o) * 384 + l * 128 + seg * 4);
      float* d = iw + o * 130 + seg * 4;
      d[0] = f.x; d[1] = f.y; d[2] = f.z; d[3] = f.w;
    }
    for (int v = t; v < 4096; v += 256) {
      int mid = v >> 5, cj = v & 31;
      cw[mid * 33 + cj] = conv_w[(size_t)((l * 128 + mid) * 256 + ckk * 32 + cj) * 9 + tap];
    }
    __syncthreads();
    const int o64 = t & 63, cs = t >> 6, o = oh * 64 + o64;
    float accs[8];
    #pragma unroll
    for (int ci = 0; ci < 8; ++ci) accs[ci] = 0.f;
    for (int mid = 0; mid < 128; ++mid) {
      float a = iw[o64 * 130 + mid];
      #pragma unroll
      for (int ci = 0; ci < 8; ++ci) accs[ci] = fmaf(a, cw[mid * 33 + cs * 8 + ci], accs[ci]);
    }
    #pragma unroll
    for (int ci = 0; ci < 8; ++ci) {
      int c = ckk * 32 + cs * 8 + ci;           // global input channel
      int ck64 = c >> 6, c64 = c & 63;
      int kh = c64 >> 5, kq3 = (c64 >> 3) & 3, el = c64 & 7;
      size_t idx = (size_t)((l * 4 + ck64) * 9 + tap) * 8192
                 + (size_t)(((o >> 4) * 2 + kh) * 512) + ((o & 15) + 16 * kq3) * 8 + el;
      wf[idx] = f2bf(accs[ci]);
    }
  } else if (b < 494) {
    // zero guards + per-image pad rows
    int z = b - 432;
    size_t base; int n16;
    if (z == 60)      { base = 0; n16 = 8192; }
    else if (z == 61) { base = (size_t)(GUARD + 3 * LVLPOS) * 256; n16 = 8192; }
    else {
      int lvl = z / 20, w = z % 20, n = w >> 1, y = (w & 1) ? 65 : 0;
      base = (size_t)(GUARD + lvl * LVLPOS + (n * 66 + y) * 114) * 256; n16 = 3648;
    }
    uint4 zz = {0u, 0u, 0u, 0u};
    uint4* d = (uint4*)(imgP + base);
    for (int v = t; v < n16; v += 256) d[v] = zz;
  } else if (b < 559) {
    int z = b - 494;
    if (z == 0) {
      if (t < 128) {
        float a = 0.f;
        for (int i = 0; i < 384; ++i) a = fmaf(img_w[t * 384 + i], conv_b[i], a);
        bias[t] = a;
      }
    } else {
      // pts_w -> fragment-major bf16
      int idx = (z - 1) * 256 + t;              // 0..16383
      int o = idx >> 7, k = idx & 127;
      int ks = k >> 5, kq = (k >> 3) & 3, el = k & 7;
      int pos = (ks * 8 + (o >> 4)) * 512 + ((o & 15) + 16 * kq) * 8 + el;
      pts_wb[pos] = f2bf(pts_w[idx]);
    }
  } else {
    int z = b - 559;
    ((float4*)statsP)[z * 256 + t] = (float4){0.f, 0.f, 0.f, 0.f};
  }
}

// =====================================================================
// NCHW fp32 -> flat padded NHWC bf16.  grid 1920 = (lvl, n, y)
// =====================================================================
__global__ __launch_bounds__(256) void k_nhwc(const float* __restrict__ img,
                                              unsigned short* __restrict__ imgP) {
  __shared__ unsigned short tile[256 * 114];   // [c][x]
  const int t = threadIdx.x;
  const int lvl = blockIdx.x / 640, r = blockIdx.x % 640, n = r >> 6, y = r & 63;
  const float4* src4 = (const float4*)(img + (size_t)(lvl * 10 + n) * 1835008 + (size_t)y * 112);
  for (int v = t; v < 7168; v += 256) {
    int c = v / 28, s = v - c * 28;
    float4 f = src4[(size_t)c * 1792 + s];
    uint2 d;
    d.x = (uint32_t)f2bf(f.x) | ((uint32_t)f2bf(f.y) << 16);
    d.y = (uint32_t)f2bf(f.z) | ((uint32_t)f2bf(f.w) << 16);
    *(uint2*)(tile + c * 114 + s * 4) = d;
  }
  __syncthreads();
  uint32_t* dst = (uint32_t*)(imgP + (size_t)(GUARD + lvl * LVLPOS + (n * 66 + y + 1) * 114) * 256);
  for (int v = t; v < 14592; v += 256) {
    int xp = v >> 7, cp = v & 127;
    uint32_t val = 0;
    if (xp >= 1 && xp <= 112) {
      int x = xp - 1;
      val = (uint32_t)tile[(2 * cp) * 114 + x] | ((uint32_t)tile[(2 * cp + 1) * 114 + x] << 16);
    }
    dst[v] = val;
  }
}

// =====================================================================
// Conv: M=64 flat pos/block (grid 1176), N=128, K=6912.
// Per-(lvl,ck,ky) A staging (66 rows x 64c, pitch 72, double-buffered,
// ONE barrier/stage); B fragments loaded register-direct from L2-resident
// fragment-major wf.  LDS 19008 B.
// launch_bounds(256,8): 8 blocks/CU capacity -> entire 1176-block grid
// co-resident (no 152-block tail; cross-block barrier decorrelation).
// =====================================================================
#define APITCH 72
static __device__ __forceinline__ void conv_stage(unsigned short* dst,
                                                  const unsigned short* __restrict__ imgP,
                                                  int s, int m0, int t) {
  int lvl = s / 12, r = s - lvl * 12;
  int ck = r / 3, ky = r - ck * 3;
  const unsigned short* base = imgP
      + (size_t)(GUARD + lvl * LVLPOS + m0 - 1 + (ky - 1) * 114) * 256 + ck * 64;
  for (int v = t; v < 528; v += 256) {          // 66 rows x 8 chunks
    int p = v >> 3, seg = v & 7;
    *(uint4*)(dst + p * APITCH + seg * 8) = *(const uint4*)(base + (size_t)p * 256 + seg * 8);
  }
}

static __device__ __forceinline__ void conv_compute(const unsigned short* As_,
                                                    const unsigned short* __restrict__ wf,
                                                    int s, int mh, int nh, int m, int kq,
                                                    f32x4 (&acc)[2][4]) {
  const unsigned short* W0 = wf + (size_t)(3 * s) * 8192 + (nh * 8) * 512 + (m + 16 * kq) * 8;
  #pragma unroll
  for (int kx = 0; kx < 3; ++kx) {
    const unsigned short* Wp = W0 + kx * 8192;
    bf16x8 bv[4][2];
    #pragma unroll
    for (int nt = 0; nt < 4; ++nt) {
      bv[nt][0] = *(const bf16x8*)(Wp + (nt * 2) * 512);
      bv[nt][1] = *(const bf16x8*)(Wp + (nt * 2 + 1) * 512);
    }
    #pragma unroll
    for (int mt = 0; mt < 2; ++mt) {
      const unsigned short* ap = As_ + (mh * 32 + mt * 16 + m + kx) * APITCH + kq * 8;
      bf16x8 a0 = *(const bf16x8*)(ap);
      bf16x8 a1 = *(const bf16x8*)(ap + 32);
      #pragma unroll
      for (int nt = 0; nt < 4; ++nt) {
        acc[mt][nt] = __builtin_amdgcn_mfma_f32_16x16x32_bf16(a0, bv[nt][0], acc[mt][nt], 0, 0, 0);
        acc[mt][nt] = __builtin_amdgcn_mfma_f32_16x16x32_bf16(a1, bv[nt][1], acc[mt][nt], 0, 0, 0);
      }
    }
  }
}

__global__ __launch_bounds__(256, 8) void k_conv(const unsigned short* __restrict__ imgP,
                                                 const unsigned short* __restrict__ wf,
                                                 const float* __restrict__ bias,
                                                 unsigned short* __restrict__ fdat) {
  __shared__ unsigned short As[2][66 * APITCH];
  const int t = threadIdx.x, lane = t & 63, wave = t >> 6;
  const int mh = wave & 1, nh = wave >> 1;
  const int m = lane & 15, kq = lane >> 4;
  const int m0 = blockIdx.x * 64;

  f32x4 acc[2][4];
  #pragma unroll
  for (int i = 0; i < 2; ++i)
    #pragma unroll
    for (int j = 0; j < 4; ++j) acc[i][j] = (f32x4){0.f, 0.f, 0.f, 0.f};

  conv_stage(As[0], imgP, 0, m0, t);
  #pragma unroll 1
  for (int s = 0; s < 36; s += 2) {
    __syncthreads();
    if (s + 1 < 36) conv_stage(As[1], imgP, s + 1, m0, t);
    conv_compute(As[0], wf, s, mh, nh, m, kq, acc);
    __syncthreads();
    if (s + 2 < 36) conv_stage(As[0], imgP, s + 2, m0, t);
    conv_compute(As[1], wf, s + 1, mh, nh, m, kq, acc);
  }
  __syncthreads();

  // epilogue: bias + bf16, LDS repack (overlays As), contiguous store
  unsigned short* Ep = &As[0][0];               // [64][128] = 16384 B <= 19008
  #pragma unroll
  for (int nt = 0; nt < 4; ++nt) {
    int oc = nh * 64 + nt * 16 + m;
    float bv = bias[oc];
    #pragma unroll
    for (int mt = 0; mt < 2; ++mt)
      #pragma unroll
      for (int rr = 0; rr < 4; ++rr)
        Ep[(mh * 32 + mt * 16 + kq * 4 + rr) * 128 + oc] = f2bf(acc[mt][nt][rr] + bv);
  }
  __syncthreads();
  unsigned short* dst = fdat + (size_t)m0 * 128;
  for (int v = t; v < 1024; v += 256)
    *(uint4*)(dst + v * 8) = *(const uint4*)(Ep + v * 8);
}

// =====================================================================
// gather (blocks 0..8191) + pts GEMM (blocks 8192..10239, 64-row tiles),
// stats fused.  LDS union 19456 B -> 8 blocks/CU (was 36864 B -> 4).
// =====================================================================
__global__ __launch_bounds__(256, 8) void k_gp(const float* __restrict__ pts_xyz,
                                               const int* __restrict__ cam_ids,
                                               const float* __restrict__ Tm,
                                               const float* __restrict__ Km,
                                               const unsigned short* __restrict__ fdat,
                                               const float* __restrict__ pts_feats,
                                               const unsigned short* __restrict__ pts_wb,
                                               unsigned short* __restrict__ img_raw,
                                               unsigned short* __restrict__ pts_raw,
                                               float* __restrict__ statsP) {
  __shared__ __align__(16) char smem[19456];
  const int t = threadIdx.x, lane = t & 63, wave = t >> 6;

  if (blockIdx.x < 8192) {
    // ---------------- gather + img stats ----------------
    float* sb = (float*)smem;                   // [128] col sums
    float* qb = sb + 128;                       // [128] col sumsq
    if (t < 128) { sb[t] = 0.f; sb[128 + t] = 0.f; }
    __syncthreads();
    const int p0 = blockIdx.x * 16 + wave * 4;
    const uint32_t* fq = (const uint32_t*)fdat;
    float s0 = 0.f, q0 = 0.f, s1 = 0.f, q1 = 0.f;
    #pragma unroll 2
    for (int j = 0; j < 4; ++j) {
      const int p = p0 + j;
      const int b = p >> 16;
      const int cam = cam_ids[p];
      const float X = pts_xyz[(size_t)p * 3], Y = pts_xyz[(size_t)p * 3 + 1], Z = pts_xyz[(size_t)p * 3 + 2];
      const float* Tc = Tm + cam * 16;
      float pcx = Tc[0] * X + Tc[1] * Y + Tc[2]  * Z + Tc[3];
      float pcy = Tc[4] * X + Tc[5] * Y + Tc[6]  * Z + Tc[7];
      float pcz = Tc[8] * X + Tc[9] * Y + Tc[10] * Z + Tc[11];
      const float* Kc = Km + cam * 9;
      float pimx = Kc[0] * 0.125f * pcx + Kc[1] * pcy          + Kc[2] * 0.125f * pcz;
      float pimy = Kc[3] * pcx          + Kc[4] * 0.125f * pcy + Kc[5] * 0.125f * pcz;
      float pimz = Kc[6] * pcx          + Kc[7] * pcy          + Kc[8] * pcz;
      float u = pimx / pimz, vv = pimy / pimz;
      float px = (u / 112.f) * 111.f;
      float py = (vv / 64.f) * 63.f;
      float x0 = floorf(px), y0 = floorf(py);
      float wx = px - x0, wy = py - y0;
      float cxf[4] = {x0, x0 + 1.f, x0, x0 + 1.f};
      float cyf[4] = {y0, y0, y0 + 1.f, y0 + 1.f};
      float cwt[4] = {(1.f - wx) * (1.f - wy), wx * (1.f - wy), (1.f - wx) * wy, wx * wy};
      const int nimg = b * 5 + cam;
      float wv[4]; int idx[4]; bool any = false;
      #pragma unroll
      for (int c4 = 0; c4 < 4; ++c4) {
        float xf = cxf[c4], yf = cyf[c4];
        bool valid = (xf >= 0.f) && (xf <= 111.f) && (yf >= 0.f) && (yf <= 63.f);
        float w = cwt[c4] * (valid ? 1.f : 0.f);
        int xi = (int)fminf(fmaxf(xf, 0.f), 111.f);
        int yi = (int)fminf(fmaxf(yf, 0.f), 63.f);
        wv[c4] = w;
        idx[c4] = (nimg * 66 + yi + 1) * 114 + xi + 1;
        any = any || (w != 0.f);
      }
      float a0 = 0.f, a1 = 0.f;
      if (any) {
        #pragma unroll
        for (int c4 = 0; c4 < 4; ++c4) {
          uint32_t d = fq[(size_t)idx[c4] * 64 + lane];
          a0 = fmaf(wv[c4], bflo(d), a0);
          a1 = fmaf(wv[c4], bfhi(d), a1);
        }
      }
      s0 += a0; q0 += a0 * a0; s1 += a1; q1 += a1 * a1;
      ((uint32_t*)img_raw)[(size_t)p * 64 + lane] =
          (uint32_t)f2bf(a0) | ((uint32_t)f2bf(a1) << 16);
    }
    atomicAdd(&sb[lane * 2], s0);
    atomicAdd(&sb[lane * 2 + 1], s1);
    atomicAdd(&qb[lane * 2], q0);
    atomicAdd(&qb[lane * 2 + 1], q1);
    __syncthreads();
    if (t < 128) {
      float* sp = statsP + (size_t)(blockIdx.x & (NPART - 1)) * 512;
      atomicAdd(sp + t, sb[t]);
      atomicAdd(sp + 128 + t, qb[t]);
    }
  } else {
    // ---------------- pts GEMM (64-row tile) + pts stats ----------------
    const int pb = blockIdx.x - 8192;                // 0..2047
    const size_t r0 = (size_t)pb * 64;
    unsigned short* As2 = (unsigned short*)smem;     // [64][136] = 17408 B
    const int mh = wave & 1, nh = wave >> 1;
    const int m = lane & 15, kq = lane >> 4;
    for (int v = t; v < 2048; v += 256) {
      int mm = v >> 5, seg = v & 31;
      float4 f = *(const float4*)(pts_feats + (r0 + mm) * 128 + seg * 4);
      uint2 d;
      d.x = (uint32_t)f2bf(f.x) | ((uint32_t)f2bf(f.y) << 16);
      d.y = (uint32_t)f2bf(f.z) | ((uint32_t)f2bf(f.w) << 16);
      *(uint2*)(As2 + mm * 136 + seg * 4) = d;
    }
    __syncthreads();
    f32x4 acc[2][4];
    #pragma unroll
    for (int i = 0; i < 2; ++i)
      #pragma unroll
      for (int jj = 0; jj < 4; ++jj) acc[i][jj] = (f32x4){0.f, 0.f, 0.f, 0.f};
    #pragma unroll
    for (int ks = 0; ks < 4; ++ks) {
      bf16x8 af0 = *(const bf16x8*)(As2 + (mh * 32 + 0 * 16 + m) * 136 + ks * 32 + kq * 8);
      bf16x8 af1 = *(const bf16x8*)(As2 + (mh * 32 + 1 * 16 + m) * 136 + ks * 32 + kq * 8);
      #pragma unroll
      for (int nt = 0; nt < 4; ++nt) {
        bf16x8 bv = *(const bf16x8*)(pts_wb + (size_t)((ks * 8 + nh * 4 + nt) * 512) + lane * 8);
        acc[0][nt] = __builtin_amdgcn_mfma_f32_16x16x32_bf16(af0, bv, acc[0][nt], 0, 0, 0);
        acc[1][nt] = __builtin_amdgcn_mfma_f32_16x16x32_bf16(af1, bv, acc[1][nt], 0, 0, 0);
      }
    }
    __syncthreads();
    #pragma unroll
    for (int mt = 0; mt < 2; ++mt)
      #pragma unroll
      for (int nt = 0; nt < 4; ++nt)
        #pragma unroll
        for (int rr = 0; rr < 4; ++rr)
          As2[(mh * 32 + mt * 16 + kq * 4 + rr) * 128 + nh * 64 + nt * 16 + m] = f2bf(acc[mt][nt][rr]);
    __syncthreads();
    unsigned short* dst = pts_raw + r0 * 128;
    for (int v = t; v < 1024; v += 256)
      *(uint4*)(dst + v * 8) = *(const uint4*)(As2 + v * 8);
    // column stats from repacked tile
    float* ps = (float*)(smem + 17408);              // [256] sums
    float* pq = (float*)(smem + 18432);              // [256] sumsq
    {
      int col = t & 127, rh = t >> 7;
      float s = 0.f, q = 0.f;
      for (int i = 0; i < 32; ++i) {
        float v = __uint_as_float((uint32_t)As2[(rh * 32 + i) * 128 + col] << 16);
        s += v; q += v * v;
      }
      ps[rh * 128 + col] = s;
      pq[rh * 128 + col] = q;
    }
    __syncthreads();
    if (t < 128) {
      float* sp = statsP + (size_t)(blockIdx.x & (NPART - 1)) * 512;
      atomicAdd(sp + 256 + t, ps[t] + ps[128 + t]);
      atomicAdd(sp + 384 + t, pq[t] + pq[128 + t]);
    }
  }
}

// =====================================================================
// finalize: reduce statsP, out = relu(a_img*img + a_pts*pts + c), fp32
// widened: uint2 loads (8B/lane) + float4 stores (16B/lane)
// =====================================================================
__global__ __launch_bounds__(256) void k_final(const unsigned short* __restrict__ img_raw,
                                               const unsigned short* __restrict__ pts_raw,
                                               const float* __restrict__ statsP,
                                               const float* __restrict__ img_gamma,
                                               const float* __restrict__ img_beta,
                                               const float* __restrict__ pts_gamma,
                                               const float* __restrict__ pts_beta,
                                               float* __restrict__ out) {
  __shared__ float sA[128], sB[128], sC[128];
  const int t = threadIdx.x;
  if (t < 128) {
    float si = 0.f, qi = 0.f, sp = 0.f, qp = 0.f;
    for (int k = 0; k < NPART; ++k) {
      const float* st = statsP + (size_t)k * 512;
      si += st[t]; qi += st[128 + t]; sp += st[256 + t]; qp += st[384 + t];
    }
    const float Nr = 131072.f;
    float mu_i = si / Nr;
    float var_i = qi / Nr - mu_i * mu_i;
    float a_i = img_gamma[t] * rsqrtf(var_i + 1e-3f);
    float mu_p = sp / Nr;
    float var_p = qp / Nr - mu_p * mu_p;
    float a_p = pts_gamma[t] * rsqrtf(var_p + 1e-3f);
    sA[t] = a_i; sB[t] = a_p;
    sC[t] = img_beta[t] + pts_beta[t] - a_i * mu_i - a_p * mu_p;
  }
  __syncthreads();
  const uint32_t* ir = (const uint32_t*)img_raw;
  const uint32_t* pr = (const uint32_t*)pts_raw;
  size_t g0 = (size_t)blockIdx.x * 2048;
  #pragma unroll
  for (int i = 0; i < 4; ++i) {
    size_t g = g0 + (size_t)i * 512 + t * 2;    // even; this thread covers g, g+1
    uint2 di = *(const uint2*)(ir + g);
    uint2 dp = *(const uint2*)(pr + g);
    int c = (int)(g & 63) * 2;                  // channels c..c+3
    float4 o;
    o.x = fmaxf(0.f, sA[c]     * bflo(di.x) + sB[c]     * bflo(dp.x) + sC[c]);
    o.y = fmaxf(0.f, sA[c + 1] * bfhi(di.x) + sB[c + 1] * bfhi(dp.x) + sC[c + 1]);
    o.z = fmaxf(0.f, sA[c + 2] * bflo(di.y) + sB[c + 2] * bflo(dp.y) + sC[c + 2]);
    o.w = fmaxf(0.f, sA[c + 3] * bfhi(di.y) + sB[c + 3] * bfhi(dp.y) + sC[c + 3]);
    *(float4*)(out + g * 2) = o;
  }
}

// =====================================================================
extern "C" void kernel_launch(void* const* d_in, const int* in_sizes, int n_in,
                              void* d_out, int out_size, void* d_ws, size_t ws_size,
                              hipStream_t stream) {
  const float* img_feats = (const float*)d_in[0];
  const float* pts_xyz   = (const float*)d_in[1];
  const float* pts_feats = (const float*)d_in[2];
  const float* Tm        = (const float*)d_in[3];
  const float* Km        = (const float*)d_in[4];
  const float* conv_w    = (const float*)d_in[5];
  const float* conv_b    = (const float*)d_in[6];
  const float* img_w     = (const float*)d_in[7];
  // d_in[8] img_b, d_in[12] pts_b cancel under BN mean subtraction
  const float* img_gamma = (const float*)d_in[9];
  const float* img_beta  = (const float*)d_in[10];
  const float* pts_w     = (const float*)d_in[11];
  const float* pts_gamma = (const float*)d_in[13];
  const float* pts_beta  = (const float*)d_in[14];
  const int*   cam_ids   = (const int*)d_in[15];

  char* wsb = (char*)d_ws;
  unsigned short* wf      = (unsigned short*)(wsb + OFF_WF);
  float*          bias    = (float*)(wsb + OFF_BIAS);
  unsigned short* pts_wb  = (unsigned short*)(wsb + OFF_PTSWB);
  float*          statsP  = (float*)(wsb + OFF_STATSP);
  unsigned short* fdat    = (unsigned short*)(wsb + OFF_FDAT);
  unsigned short* imgP    = (unsigned short*)(wsb + OFF_IMGP);
  unsigned short* img_raw = (unsigned short*)(wsb + OFF_IRAW);
  unsigned short* pts_raw = (unsigned short*)(wsb + OFF_PRAW);

  k_setup<<<dim3(567), dim3(256), 0, stream>>>(img_w, conv_w, conv_b, pts_w,
                                               wf, bias, pts_wb, imgP, statsP);
  k_nhwc<<<dim3(1920), dim3(256), 0, stream>>>(img_feats, imgP);
  k_conv<<<dim3(1176), dim3(256), 0, stream>>>(imgP, wf, bias, fdat);
  k_gp<<<dim3(10240), dim3(256), 0, stream>>>(pts_xyz, cam_ids, Tm, Km, fdat,
                                              pts_feats, pts_wb, img_raw, pts_raw, statsP);
  k_final<<<dim3(4096), dim3(256), 0, stream>>>(img_raw, pts_raw, statsP,
                                                img_gamma, img_beta, pts_gamma, pts_beta,
                                                (float*)d_out);
}

// Round 2
// 690.168 us; speedup vs baseline: 1.3899x; 1.3899x over previous
//
#include <hip/hip_runtime.h>
#include <cstdint>

// ---------------- problem constants ----------------
#define LVLPOS 75240          // 10*66*114 flat padded positions per level
#define GUARD  256            // zero guard positions before/after imgP data
#define NPART  16             // stats partial copies (atomic contention spread)

using f32x4  = __attribute__((ext_vector_type(4))) float;
using bf16x8 = __attribute__((ext_vector_type(8))) __bf16;

static __device__ __forceinline__ unsigned short f2bf(float f) {
  unsigned int u = __float_as_uint(f);
  u += 0x7fffu + ((u >> 16) & 1u);     // round-to-nearest-even
  return (unsigned short)(u >> 16);
}
static __device__ __forceinline__ float bflo(uint32_t d) { return __uint_as_float(d << 16); }
static __device__ __forceinline__ float bfhi(uint32_t d) { return __uint_as_float(d & 0xffff0000u); }

// ---------------- ws layout (bytes) ----------------
// wf     : [3][ck64:4][tap:9][frag 8192] bf16 (fragment-major folded W)  1,769,472
// bias   : [128] f32                                                           512
// pts_wb : [128][128] bf16, fragment-major                                  32,768
// statsP : [16][512] f32 partials                                           32,768
// fdat   : [75264][128] bf16 (level-summed conv output, padded layout)  19,267,584
// imgP   : [(256+3*75240+256)][256] bf16 flat padded NHWC               115,830,784
// img_raw/pts_raw (each 33,554,432) ALIAS imgP (imgP dead after k_conv)
#define OFF_WF     ((size_t)0)
#define OFF_BIAS   ((size_t)1769472)
#define OFF_PTSWB  ((size_t)1769984)
#define OFF_STATSP ((size_t)1802752)
#define OFF_FDAT   ((size_t)1835520)
#define OFF_IMGP   ((size_t)21103104)
#define OFF_IRAW   OFF_IMGP
#define OFF_PRAW   (OFF_IMGP + (size_t)33554432)

// =====================================================================
// setup: fold weights (432), zero imgP pads (62), bias+pts prepack (65),
// zero statsP (8).  grid 567.
// =====================================================================
__global__ __launch_bounds__(256) void k_setup(const float* __restrict__ img_w,
                                               const float* __restrict__ conv_w,
                                               const float* __restrict__ conv_b,
                                               const float* __restrict__ pts_w,
                                               unsigned short* __restrict__ wf,
                                               float* __restrict__ bias,
                                               unsigned short* __restrict__ pts_wb,
                                               unsigned short* __restrict__ imgP,
                                               float* __restrict__ statsP) {
  __shared__ float smem[12544];                 // iw 64x130 + cw 128x33 = 50176 B
  const int b = blockIdx.x, t = threadIdx.x;
  if (b < 432) {
    // fold: wf[l][ck64][tap][frag]; block = (l, tap, ck32, o-half)
    int z = b >> 1, oh = b & 1;
    int l = z / 72, r = z % 72, tap = r / 8, ckk = r % 8;
    float* iw = smem;                           // [64 o][130]
    float* cw = smem + 8320;                    // [128 mid][33]
    for (int v = t; v < 2048; v += 256) {
      int o = v >> 5, seg = v & 31;
      float4 f = *(const float4*)(img_w + (size_t)(oh * 64 + o) * 384 + l * 128 + seg * 4);
      float* d = iw + o * 130 + seg * 4;
      d[0] = f.x; d[1] = f.y; d[2] = f.z; d[3] = f.w;
    }
    for (int v = t; v < 4096; v += 256) {
      int mid = v >> 5, cj = v & 31;
      cw[mid * 33 + cj] = conv_w[(size_t)((l * 128 + mid) * 256 + ckk * 32 + cj) * 9 + tap];
    }
    __syncthreads();
    const int o64 = t & 63, cs = t >> 6, o = oh * 64 + o64;
    float accs[8];
    #pragma unroll
    for (int ci = 0; ci < 8; ++ci) accs[ci] = 0.f;
    for (int mid = 0; mid < 128; ++mid) {
      float a = iw[o64 * 130 + mid];
      #pragma unroll
      for (int ci = 0; ci < 8; ++ci) accs[ci] = fmaf(a, cw[mid * 33 + cs * 8 + ci], accs[ci]);
    }
    #pragma unroll
    for (int ci = 0; ci < 8; ++ci) {
      int c = ckk * 32 + cs * 8 + ci;           // global input channel
      int ck64 = c >> 6, c64 = c & 63;
      int kh = c64 >> 5, kq3 = (c64 >> 3) & 3, el = c64 & 7;
      size_t idx = (size_t)((l * 4 + ck64) * 9 + tap) * 8192
                 + (size_t)(((o >> 4) * 2 + kh) * 512) + ((o & 15) + 16 * kq3) * 8 + el;
      wf[idx] = f2bf(accs[ci]);
    }
  } else if (b < 494) {
    // zero guards + per-image pad rows
    int z = b - 432;
    size_t base; int n16;
    if (z == 60)      { base = 0; n16 = 8192; }
    else if (z == 61) { base = (size_t)(GUARD + 3 * LVLPOS) * 256; n16 = 8192; }
    else {
      int lvl = z / 20, w = z % 20, n = w >> 1, y = (w & 1) ? 65 : 0;
      base = (size_t)(GUARD + lvl * LVLPOS + (n * 66 + y) * 114) * 256; n16 = 3648;
    }
    uint4 zz = {0u, 0u, 0u, 0u};
    uint4* d = (uint4*)(imgP + base);
    for (int v = t; v < n16; v += 256) d[v] = zz;
  } else if (b < 559) {
    int z = b - 494;
    if (z == 0) {
      if (t < 128) {
        float a = 0.f;
        for (int i = 0; i < 384; ++i) a = fmaf(img_w[t * 384 + i], conv_b[i], a);
        bias[t] = a;
      }
    } else {
      // pts_w -> fragment-major bf16
      int idx = (z - 1) * 256 + t;              // 0..16383
      int o = idx >> 7, k = idx & 127;
      int ks = k >> 5, kq = (k >> 3) & 3, el = k & 7;
      int pos = (ks * 8 + (o >> 4)) * 512 + ((o & 15) + 16 * kq) * 8 + el;
      pts_wb[pos] = f2bf(pts_w[idx]);
    }
  } else {
    int z = b - 559;
    ((float4*)statsP)[z * 256 + t] = (float4){0.f, 0.f, 0.f, 0.f};
  }
}

// =====================================================================
// NCHW fp32 -> flat padded NHWC bf16.  grid 1920 = (lvl, n, y)
// =====================================================================
__global__ __launch_bounds__(256) void k_nhwc(const float* __restrict__ img,
                                              unsigned short* __restrict__ imgP) {
  __shared__ unsigned short tile[256 * 114];   // [c][x]
  const int t = threadIdx.x;
  const int lvl = blockIdx.x / 640, r = blockIdx.x % 640, n = r >> 6, y = r & 63;
  const float4* src4 = (const float4*)(img + (size_t)(lvl * 10 + n) * 1835008 + (size_t)y * 112);
  for (int v = t; v < 7168; v += 256) {
    int c = v / 28, s = v - c * 28;
    float4 f = src4[(size_t)c * 1792 + s];
    uint2 d;
    d.x = (uint32_t)f2bf(f.x) | ((uint32_t)f2bf(f.y) << 16);
    d.y = (uint32_t)f2bf(f.z) | ((uint32_t)f2bf(f.w) << 16);
    *(uint2*)(tile + c * 114 + s * 4) = d;
  }
  __syncthreads();
  uint32_t* dst = (uint32_t*)(imgP + (size_t)(GUARD + lvl * LVLPOS + (n * 66 + y + 1) * 114) * 256);
  for (int v = t; v < 14592; v += 256) {
    int xp = v >> 7, cp = v & 127;
    uint32_t val = 0;
    if (xp >= 1 && xp <= 112) {
      int x = xp - 1;
      val = (uint32_t)tile[(2 * cp) * 114 + x] | ((uint32_t)tile[(2 * cp + 1) * 114 + x] << 16);
    }
    dst[v] = val;
  }
}

// =====================================================================
// Conv: M=64 flat pos/block (grid 1176), N=128, K=6912.
// Wave decomposition 1x4: each wave = full 64 rows x 32-col quadrant.
// -> B(wf) fragment loads per wave halve (24->12) and all 4 waves read
//    DISTINCT wf rows (was: nh-pairs duplicated) -> block wf L2 traffic
//    halves (~20 TB/s -> ~10 TB/s aggregate).  A ds_reads double (cheap).
// acc[4][2]=32 AGPR (same), bv live set halves -> regs <= round-0's 48.
// launch_bounds(256,4): 128 regs/wave — round-1's (256,8) forced 32 VGPR
// and spilled (WRITE_SIZE 522 MB). Do not raise.
// =====================================================================
#define APITCH 72
static __device__ __forceinline__ void conv_stage(unsigned short* dst,
                                                  const unsigned short* __restrict__ imgP,
                                                  int s, int m0, int t) {
  int lvl = s / 12, r = s - lvl * 12;
  int ck = r / 3, ky = r - ck * 3;
  const unsigned short* base = imgP
      + (size_t)(GUARD + lvl * LVLPOS + m0 - 1 + (ky - 1) * 114) * 256 + ck * 64;
  for (int v = t; v < 528; v += 256) {          // 66 rows x 8 chunks
    int p = v >> 3, seg = v & 7;
    *(uint4*)(dst + p * APITCH + seg * 8) = *(const uint4*)(base + (size_t)p * 256 + seg * 8);
  }
}

static __device__ __forceinline__ void conv_compute(const unsigned short* As_,
                                                    const unsigned short* __restrict__ wf,
                                                    int s, int nh, int m, int kq,
                                                    f32x4 (&acc)[4][2]) {
  // wave nh covers output cols nh*32 .. nh*32+31 (fragment rows nh*4 .. nh*4+3)
  const unsigned short* W0 = wf + (size_t)(3 * s) * 8192 + (nh * 4) * 512 + (m + 16 * kq) * 8;
  #pragma unroll
  for (int kx = 0; kx < 3; ++kx) {
    const unsigned short* Wp = W0 + kx * 8192;
    bf16x8 bv[2][2];
    #pragma unroll
    for (int nt = 0; nt < 2; ++nt) {
      bv[nt][0] = *(const bf16x8*)(Wp + (nt * 2) * 512);
      bv[nt][1] = *(const bf16x8*)(Wp + (nt * 2 + 1) * 512);
    }
    #pragma unroll
    for (int mt = 0; mt < 4; ++mt) {
      const unsigned short* ap = As_ + (mt * 16 + m + kx) * APITCH + kq * 8;
      bf16x8 a0 = *(const bf16x8*)(ap);
      bf16x8 a1 = *(const bf16x8*)(ap + 32);
      #pragma unroll
      for (int nt = 0; nt < 2; ++nt) {
        acc[mt][nt] = __builtin_amdgcn_mfma_f32_16x16x32_bf16(a0, bv[nt][0], acc[mt][nt], 0, 0, 0);
        acc[mt][nt] = __builtin_amdgcn_mfma_f32_16x16x32_bf16(a1, bv[nt][1], acc[mt][nt], 0, 0, 0);
      }
    }
  }
}

__global__ __launch_bounds__(256, 4) void k_conv(const unsigned short* __restrict__ imgP,
                                                 const unsigned short* __restrict__ wf,
                                                 const float* __restrict__ bias,
                                                 unsigned short* __restrict__ fdat) {
  __shared__ unsigned short As[2][66 * APITCH];
  const int t = threadIdx.x, lane = t & 63, wave = t >> 6;
  const int nh = wave;                          // 1x4 decomposition
  const int m = lane & 15, kq = lane >> 4;
  const int m0 = blockIdx.x * 64;

  f32x4 acc[4][2];
  #pragma unroll
  for (int i = 0; i < 4; ++i)
    #pragma unroll
    for (int j = 0; j < 2; ++j) acc[i][j] = (f32x4){0.f, 0.f, 0.f, 0.f};

  conv_stage(As[0], imgP, 0, m0, t);
  #pragma unroll 1
  for (int s = 0; s < 36; s += 2) {
    __syncthreads();
    if (s + 1 < 36) conv_stage(As[1], imgP, s + 1, m0, t);
    conv_compute(As[0], wf, s, nh, m, kq, acc);
    __syncthreads();
    if (s + 2 < 36) conv_stage(As[0], imgP, s + 2, m0, t);
    conv_compute(As[1], wf, s + 1, nh, m, kq, acc);
  }
  __syncthreads();

  // epilogue: bias + bf16, LDS repack (overlays As), contiguous store
  unsigned short* Ep = &As[0][0];               // [64][128] = 16384 B <= 19008
  #pragma unroll
  for (int nt = 0; nt < 2; ++nt) {
    int oc = nh * 32 + nt * 16 + m;
    float bb = bias[oc];
    #pragma unroll
    for (int mt = 0; mt < 4; ++mt)
      #pragma unroll
      for (int rr = 0; rr < 4; ++rr)
        Ep[(mt * 16 + kq * 4 + rr) * 128 + oc] = f2bf(acc[mt][nt][rr] + bb);
  }
  __syncthreads();
  unsigned short* dst = fdat + (size_t)m0 * 128;
  for (int v = t; v < 1024; v += 256)
    *(uint4*)(dst + v * 8) = *(const uint4*)(Ep + v * 8);
}

// =====================================================================
// gather (blocks 0..8191) + pts GEMM (blocks 8192..10239, 64-row tiles),
// stats fused.  LDS union 19456 B (occupancy from LDS: up to 8/CU;
// registers uncapped — no forced spill).
// =====================================================================
__global__ __launch_bounds__(256) void k_gp(const float* __restrict__ pts_xyz,
                                            const int* __restrict__ cam_ids,
                                            const float* __restrict__ Tm,
                                            const float* __restrict__ Km,
                                            const unsigned short* __restrict__ fdat,
                                            const float* __restrict__ pts_feats,
                                            const unsigned short* __restrict__ pts_wb,
                                            unsigned short* __restrict__ img_raw,
                                            unsigned short* __restrict__ pts_raw,
                                            float* __restrict__ statsP) {
  __shared__ __align__(16) char smem[19456];
  const int t = threadIdx.x, lane = t & 63, wave = t >> 6;

  if (blockIdx.x < 8192) {
    // ---------------- gather + img stats ----------------
    float* sb = (float*)smem;                   // [128] col sums
    float* qb = sb + 128;                       // [128] col sumsq
    if (t < 128) { sb[t] = 0.f; sb[128 + t] = 0.f; }
    __syncthreads();
    const int p0 = blockIdx.x * 16 + wave * 4;
    const uint32_t* fq = (const uint32_t*)fdat;
    float s0 = 0.f, q0 = 0.f, s1 = 0.f, q1 = 0.f;
    #pragma unroll 2
    for (int j = 0; j < 4; ++j) {
      const int p = p0 + j;
      const int b = p >> 16;
      const int cam = cam_ids[p];
      const float X = pts_xyz[(size_t)p * 3], Y = pts_xyz[(size_t)p * 3 + 1], Z = pts_xyz[(size_t)p * 3 + 2];
      const float* Tc = Tm + cam * 16;
      float pcx = Tc[0] * X + Tc[1] * Y + Tc[2]  * Z + Tc[3];
      float pcy = Tc[4] * X + Tc[5] * Y + Tc[6]  * Z + Tc[7];
      float pcz = Tc[8] * X + Tc[9] * Y + Tc[10] * Z + Tc[11];
      const float* Kc = Km + cam * 9;
      float pimx = Kc[0] * 0.125f * pcx + Kc[1] * pcy          + Kc[2] * 0.125f * pcz;
      float pimy = Kc[3] * pcx          + Kc[4] * 0.125f * pcy + Kc[5] * 0.125f * pcz;
      float pimz = Kc[6] * pcx          + Kc[7] * pcy          + Kc[8] * pcz;
      float u = pimx / pimz, vv = pimy / pimz;
      float px = (u / 112.f) * 111.f;
      float py = (vv / 64.f) * 63.f;
      float x0 = floorf(px), y0 = floorf(py);
      float wx = px - x0, wy = py - y0;
      float cxf[4] = {x0, x0 + 1.f, x0, x0 + 1.f};
      float cyf[4] = {y0, y0, y0 + 1.f, y0 + 1.f};
      float cwt[4] = {(1.f - wx) * (1.f - wy), wx * (1.f - wy), (1.f - wx) * wy, wx * wy};
      const int nimg = b * 5 + cam;
      float wv[4]; int idx[4]; bool any = false;
      #pragma unroll
      for (int c4 = 0; c4 < 4; ++c4) {
        float xf = cxf[c4], yf = cyf[c4];
        bool valid = (xf >= 0.f) && (xf <= 111.f) && (yf >= 0.f) && (yf <= 63.f);
        float w = cwt[c4] * (valid ? 1.f : 0.f);
        int xi = (int)fminf(fmaxf(xf, 0.f), 111.f);
        int yi = (int)fminf(fmaxf(yf, 0.f), 63.f);
        wv[c4] = w;
        idx[c4] = (nimg * 66 + yi + 1) * 114 + xi + 1;
        any = any || (w != 0.f);
      }
      float a0 = 0.f, a1 = 0.f;
      if (any) {
        #pragma unroll
        for (int c4 = 0; c4 < 4; ++c4) {
          uint32_t d = fq[(size_t)idx[c4] * 64 + lane];
          a0 = fmaf(wv[c4], bflo(d), a0);
          a1 = fmaf(wv[c4], bfhi(d), a1);
        }
      }
      s0 += a0; q0 += a0 * a0; s1 += a1; q1 += a1 * a1;
      ((uint32_t*)img_raw)[(size_t)p * 64 + lane] =
          (uint32_t)f2bf(a0) | ((uint32_t)f2bf(a1) << 16);
    }
    atomicAdd(&sb[lane * 2], s0);
    atomicAdd(&sb[lane * 2 + 1], s1);
    atomicAdd(&qb[lane * 2], q0);
    atomicAdd(&qb[lane * 2 + 1], q1);
    __syncthreads();
    if (t < 128) {
      float* sp = statsP + (size_t)(blockIdx.x & (NPART - 1)) * 512;
      atomicAdd(sp + t, sb[t]);
      atomicAdd(sp + 128 + t, qb[t]);
    }
  } else {
    // ---------------- pts GEMM (64-row tile) + pts stats ----------------
    const int pb = blockIdx.x - 8192;                // 0..2047
    const size_t r0 = (size_t)pb * 64;
    unsigned short* As2 = (unsigned short*)smem;     // [64][136] = 17408 B
    const int mh = wave & 1, nh = wave >> 1;
    const int m = lane & 15, kq = lane >> 4;
    for (int v = t; v < 2048; v += 256) {
      int mm = v >> 5, seg = v & 31;
      float4 f = *(const float4*)(pts_feats + (r0 + mm) * 128 + seg * 4);
      uint2 d;
      d.x = (uint32_t)f2bf(f.x) | ((uint32_t)f2bf(f.y) << 16);
      d.y = (uint32_t)f2bf(f.z) | ((uint32_t)f2bf(f.w) << 16);
      *(uint2*)(As2 + mm * 136 + seg * 4) = d;
    }
    __syncthreads();
    f32x4 acc[2][4];
    #pragma unroll
    for (int i = 0; i < 2; ++i)
      #pragma unroll
      for (int jj = 0; jj < 4; ++jj) acc[i][jj] = (f32x4){0.f, 0.f, 0.f, 0.f};
    #pragma unroll
    for (int ks = 0; ks < 4; ++ks) {
      bf16x8 af0 = *(const bf16x8*)(As2 + (mh * 32 + 0 * 16 + m) * 136 + ks * 32 + kq * 8);
      bf16x8 af1 = *(const bf16x8*)(As2 + (mh * 32 + 1 * 16 + m) * 136 + ks * 32 + kq * 8);
      #pragma unroll
      for (int nt = 0; nt < 4; ++nt) {
        bf16x8 bv = *(const bf16x8*)(pts_wb + (size_t)((ks * 8 + nh * 4 + nt) * 512) + lane * 8);
        acc[0][nt] = __builtin_amdgcn_mfma_f32_16x16x32_bf16(af0, bv, acc[0][nt], 0, 0, 0);
        acc[1][nt] = __builtin_amdgcn_mfma_f32_16x16x32_bf16(af1, bv, acc[1][nt], 0, 0, 0);
      }
    }
    __syncthreads();
    #pragma unroll
    for (int mt = 0; mt < 2; ++mt)
      #pragma unroll
      for (int nt = 0; nt < 4; ++nt)
        #pragma unroll
        for (int rr = 0; rr < 4; ++rr)
          As2[(mh * 32 + mt * 16 + kq * 4 + rr) * 128 + nh * 64 + nt * 16 + m] = f2bf(acc[mt][nt][rr]);
    __syncthreads();
    unsigned short* dst = pts_raw + r0 * 128;
    for (int v = t; v < 1024; v += 256)
      *(uint4*)(dst + v * 8) = *(const uint4*)(As2 + v * 8);
    // column stats from repacked tile
    float* ps = (float*)(smem + 17408);              // [256] sums
    float* pq = (float*)(smem + 18432);              // [256] sumsq
    {
      int col = t & 127, rh = t >> 7;
      float s = 0.f, q = 0.f;
      for (int i = 0; i < 32; ++i) {
        float v = __uint_as_float((uint32_t)As2[(rh * 32 + i) * 128 + col] << 16);
        s += v; q += v * v;
      }
      ps[rh * 128 + col] = s;
      pq[rh * 128 + col] = q;
    }
    __syncthreads();
    if (t < 128) {
      float* sp = statsP + (size_t)(blockIdx.x & (NPART - 1)) * 512;
      atomicAdd(sp + 256 + t, ps[t] + ps[128 + t]);
      atomicAdd(sp + 384 + t, pq[t] + pq[128 + t]);
    }
  }
}

// =====================================================================
// finalize: reduce statsP, out = relu(a_img*img + a_pts*pts + c), fp32
// widened: uint2 loads (8B/lane) + float4 stores (16B/lane)
// =====================================================================
__global__ __launch_bounds__(256) void k_final(const unsigned short* __restrict__ img_raw,
                                               const unsigned short* __restrict__ pts_raw,
                                               const float* __restrict__ statsP,
                                               const float* __restrict__ img_gamma,
                                               const float* __restrict__ img_beta,
                                               const float* __restrict__ pts_gamma,
                                               const float* __restrict__ pts_beta,
                                               float* __restrict__ out) {
  __shared__ float sA[128], sB[128], sC[128];
  const int t = threadIdx.x;
  if (t < 128) {
    float si = 0.f, qi = 0.f, sp = 0.f, qp = 0.f;
    for (int k = 0; k < NPART; ++k) {
      const float* st = statsP + (size_t)k * 512;
      si += st[t]; qi += st[128 + t]; sp += st[256 + t]; qp += st[384 + t];
    }
    const float Nr = 131072.f;
    float mu_i = si / Nr;
    float var_i = qi / Nr - mu_i * mu_i;
    float a_i = img_gamma[t] * rsqrtf(var_i + 1e-3f);
    float mu_p = sp / Nr;
    float var_p = qp / Nr - mu_p * mu_p;
    float a_p = pts_gamma[t] * rsqrtf(var_p + 1e-3f);
    sA[t] = a_i; sB[t] = a_p;
    sC[t] = img_beta[t] + pts_beta[t] - a_i * mu_i - a_p * mu_p;
  }
  __syncthreads();
  const uint32_t* ir = (const uint32_t*)img_raw;
  const uint32_t* pr = (const uint32_t*)pts_raw;
  size_t g0 = (size_t)blockIdx.x * 2048;
  #pragma unroll
  for (int i = 0; i < 4; ++i) {
    size_t g = g0 + (size_t)i * 512 + t * 2;    // even; this thread covers g, g+1
    uint2 di = *(const uint2*)(ir + g);
    uint2 dp = *(const uint2*)(pr + g);
    int c = (int)(g & 63) * 2;                  // channels c..c+3
    float4 o;
    o.x = fmaxf(0.f, sA[c]     * bflo(di.x) + sB[c]     * bflo(dp.x) + sC[c]);
    o.y = fmaxf(0.f, sA[c + 1] * bfhi(di.x) + sB[c + 1] * bfhi(dp.x) + sC[c + 1]);
    o.z = fmaxf(0.f, sA[c + 2] * bflo(di.y) + sB[c + 2] * bflo(dp.y) + sC[c + 2]);
    o.w = fmaxf(0.f, sA[c + 3] * bfhi(di.y) + sB[c + 3] * bfhi(dp.y) + sC[c + 3]);
    *(float4*)(out + g * 2) = o;
  }
}

// =====================================================================
extern "C" void kernel_launch(void* const* d_in, const int* in_sizes, int n_in,
                              void* d_out, int out_size, void* d_ws, size_t ws_size,
                              hipStream_t stream) {
  const float* img_feats = (const float*)d_in[0];
  const float* pts_xyz   = (const float*)d_in[1];
  const float* pts_feats = (const float*)d_in[2];
  const float* Tm        = (const float*)d_in[3];
  const float* Km        = (const float*)d_in[4];
  const float* conv_w    = (const float*)d_in[5];
  const float* conv_b    = (const float*)d_in[6];
  const float* img_w     = (const float*)d_in[7];
  // d_in[8] img_b, d_in[12] pts_b cancel under BN mean subtraction
  const float* img_gamma = (const float*)d_in[9];
  const float* img_beta  = (const float*)d_in[10];
  const float* pts_w     = (const float*)d_in[11];
  const float* pts_gamma = (const float*)d_in[13];
  const float* pts_beta  = (const float*)d_in[14];
  const int*   cam_ids   = (const int*)d_in[15];

  char* wsb = (char*)d_ws;
  unsigned short* wf      = (unsigned short*)(wsb + OFF_WF);
  float*          bias    = (float*)(wsb + OFF_BIAS);
  unsigned short* pts_wb  = (unsigned short*)(wsb + OFF_PTSWB);
  float*          statsP  = (float*)(wsb + OFF_STATSP);
  unsigned short* fdat    = (unsigned short*)(wsb + OFF_FDAT);
  unsigned short* imgP    = (unsigned short*)(wsb + OFF_IMGP);
  unsigned short* img_raw = (unsigned short*)(wsb + OFF_IRAW);
  unsigned short* pts_raw = (unsigned short*)(wsb + OFF_PRAW);

  k_setup<<<dim3(567), dim3(256), 0, stream>>>(img_w, conv_w, conv_b, pts_w,
                                               wf, bias, pts_wb, imgP, statsP);
  k_nhwc<<<dim3(1920), dim3(256), 0, stream>>>(img_feats, imgP);
  k_conv<<<dim3(1176), dim3(256), 0, stream>>>(imgP, wf, bias, fdat);
  k_gp<<<dim3(10240), dim3(256), 0, stream>>>(pts_xyz, cam_ids, Tm, Km, fdat,
                                              pts_feats, pts_wb, img_raw, pts_raw, statsP);
  k_final<<<dim3(4096), dim3(256), 0, stream>>>(img_raw, pts_raw, statsP,
                                                img_gamma, img_beta, pts_gamma, pts_beta,
                                                (float*)d_out);
}

// Round 3
// 658.028 us; speedup vs baseline: 1.4578x; 1.0488x over previous
//
#include <hip/hip_runtime.h>
#include <cstdint>

// ---------------- problem constants ----------------
#define LVLPOS 75240          // 10*66*114 flat padded positions per level
#define GUARD  256            // zero guard positions before/after imgP data
#define NPART  64             // stats partial copies (atomic contention spread)

using f32x4  = __attribute__((ext_vector_type(4))) float;
using bf16x8 = __attribute__((ext_vector_type(8))) __bf16;

static __device__ __forceinline__ unsigned short f2bf(float f) {
  unsigned int u = __float_as_uint(f);
  u += 0x7fffu + ((u >> 16) & 1u);     // round-to-nearest-even
  return (unsigned short)(u >> 16);
}
static __device__ __forceinline__ float bflo(uint32_t d) { return __uint_as_float(d << 16); }
static __device__ __forceinline__ float bfhi(uint32_t d) { return __uint_as_float(d & 0xffff0000u); }

// ---------------- ws layout (bytes) ----------------
// wf     : [3][ck64:4][tap:9][frag 8192] bf16 (fragment-major folded W)  1,769,472
// bias   : [128] f32                                                           512
// pts_wb : [128][128] bf16, fragment-major                                  32,768
// statsP : [64][512] f32 partials                                          131,072
// fdat   : [75264][128] bf16 (level-summed conv output, padded layout)  19,267,584
// imgP   : [(256+3*75240+256)][256] bf16 flat padded NHWC               115,830,784
// img_raw/pts_raw (each 33,554,432) ALIAS imgP (imgP dead after k_conv)
#define OFF_WF     ((size_t)0)
#define OFF_BIAS   ((size_t)1769472)
#define OFF_PTSWB  ((size_t)1769984)
#define OFF_STATSP ((size_t)1802752)
#define OFF_FDAT   ((size_t)1933824)
#define OFF_IMGP   ((size_t)21201408)
#define OFF_IRAW   OFF_IMGP
#define OFF_PRAW   (OFF_IMGP + (size_t)33554432)

// =====================================================================
// k_pre: fused nhwc transpose (blocks 0..1919) + setup (fold 432,
// imgP pad zero 62, bias+pts prepack 65, statsP zero 32).  grid 2511.
// nhwc blocks are BW-bound, setup fold is compute-bound -> fold hides
// under nhwc instead of serializing as a separate launch.
// nhwc writes imgP data rows + x-pads; setup zeroes y-pad rows/guards:
// disjoint addresses, safe to run concurrently.
// =====================================================================
__global__ __launch_bounds__(256) void k_pre(const float* __restrict__ img,
                                             const float* __restrict__ img_w,
                                             const float* __restrict__ conv_w,
                                             const float* __restrict__ conv_b,
                                             const float* __restrict__ pts_w,
                                             unsigned short* __restrict__ wf,
                                             float* __restrict__ bias,
                                             unsigned short* __restrict__ pts_wb,
                                             unsigned short* __restrict__ imgP,
                                             float* __restrict__ statsP) {
  __shared__ __align__(16) char smem_raw[58368];
  const int t = threadIdx.x;
  if (blockIdx.x < 1920) {
    // ---------------- NCHW fp32 -> flat padded NHWC bf16 ----------------
    unsigned short* tile = (unsigned short*)smem_raw;   // [256 c][114 x]
    const int lvl = blockIdx.x / 640, r = blockIdx.x % 640, n = r >> 6, y = r & 63;
    const float4* src4 = (const float4*)(img + (size_t)(lvl * 10 + n) * 1835008 + (size_t)y * 112);
    for (int v = t; v < 7168; v += 256) {
      int c = v / 28, s = v - c * 28;
      float4 f = src4[(size_t)c * 1792 + s];
      uint2 d;
      d.x = (uint32_t)f2bf(f.x) | ((uint32_t)f2bf(f.y) << 16);
      d.y = (uint32_t)f2bf(f.z) | ((uint32_t)f2bf(f.w) << 16);
      *(uint2*)(tile + c * 114 + s * 4) = d;
    }
    __syncthreads();
    // store widened to uint2 (8 B/lane): 7296 pairs of dwords
    uint32_t* dst = (uint32_t*)(imgP + (size_t)(GUARD + lvl * LVLPOS + (n * 66 + y + 1) * 114) * 256);
    for (int u = t; u < 7296; u += 256) {
      int xp = u >> 6, cp = (u & 63) * 2;         // dwords cp, cp+1 of row xp
      uint2 val = {0u, 0u};
      if (xp >= 1 && xp <= 112) {
        int x = xp - 1;
        val.x = (uint32_t)tile[(2 * cp) * 114 + x]     | ((uint32_t)tile[(2 * cp + 1) * 114 + x] << 16);
        val.y = (uint32_t)tile[(2 * cp + 2) * 114 + x] | ((uint32_t)tile[(2 * cp + 3) * 114 + x] << 16);
      }
      *(uint2*)(dst + (size_t)xp * 128 + cp) = val;
    }
    return;
  }
  const int b = blockIdx.x - 1920;
  if (b < 432) {
    // fold: wf[l][ck64][tap][frag]; block = (l, tap, ck32, o-half)
    int z = b >> 1, oh = b & 1;
    int l = z / 72, r = z % 72, tap = r / 8, ckk = r % 8;
    float* iw = (float*)smem_raw;               // [64 o][130]
    float* cw = (float*)smem_raw + 8320;        // [128 mid][33]
    for (int v = t; v < 2048; v += 256) {
      int o = v >> 5, seg = v & 31;
      float4 f = *(const float4*)(img_w + (size_t)(oh * 64 + o) * 384 + l * 128 + seg * 4);
      float* d = iw + o * 130 + seg * 4;
      d[0] = f.x; d[1] = f.y; d[2] = f.z; d[3] = f.w;
    }
    for (int v = t; v < 4096; v += 256) {
      int mid = v >> 5, cj = v & 31;
      cw[mid * 33 + cj] = conv_w[(size_t)((l * 128 + mid) * 256 + ckk * 32 + cj) * 9 + tap];
    }
    __syncthreads();
    const int o64 = t & 63, cs = t >> 6, o = oh * 64 + o64;
    float accs[8];
    #pragma unroll
    for (int ci = 0; ci < 8; ++ci) accs[ci] = 0.f;
    for (int mid = 0; mid < 128; ++mid) {
      float a = iw[o64 * 130 + mid];
      #pragma unroll
      for (int ci = 0; ci < 8; ++ci) accs[ci] = fmaf(a, cw[mid * 33 + cs * 8 + ci], accs[ci]);
    }
    #pragma unroll
    for (int ci = 0; ci < 8; ++ci) {
      int c = ckk * 32 + cs * 8 + ci;           // global input channel
      int ck64 = c >> 6, c64 = c & 63;
      int kh = c64 >> 5, kq3 = (c64 >> 3) & 3, el = c64 & 7;
      size_t idx = (size_t)((l * 4 + ck64) * 9 + tap) * 8192
                 + (size_t)(((o >> 4) * 2 + kh) * 512) + ((o & 15) + 16 * kq3) * 8 + el;
      wf[idx] = f2bf(accs[ci]);
    }
  } else if (b < 494) {
    // zero guards + per-image y-pad rows
    int z = b - 432;
    size_t base; int n16;
    if (z == 60)      { base = 0; n16 = 8192; }
    else if (z == 61) { base = (size_t)(GUARD + 3 * LVLPOS) * 256; n16 = 8192; }
    else {
      int lvl = z / 20, w = z % 20, n = w >> 1, y = (w & 1) ? 65 : 0;
      base = (size_t)(GUARD + lvl * LVLPOS + (n * 66 + y) * 114) * 256; n16 = 3648;
    }
    uint4 zz = {0u, 0u, 0u, 0u};
    uint4* d = (uint4*)(imgP + base);
    for (int v = t; v < n16; v += 256) d[v] = zz;
  } else if (b < 559) {
    int z = b - 494;
    if (z == 0) {
      if (t < 128) {
        float a = 0.f;
        for (int i = 0; i < 384; ++i) a = fmaf(img_w[t * 384 + i], conv_b[i], a);
        bias[t] = a;
      }
    } else {
      // pts_w -> fragment-major bf16
      int idx = (z - 1) * 256 + t;              // 0..16383
      int o = idx >> 7, k = idx & 127;
      int ks = k >> 5, kq = (k >> 3) & 3, el = k & 7;
      int pos = (ks * 8 + (o >> 4)) * 512 + ((o & 15) + 16 * kq) * 8 + el;
      pts_wb[pos] = f2bf(pts_w[idx]);
    }
  } else {
    int z = b - 559;                            // 0..31 -> 64*512 floats
    ((float4*)statsP)[z * 256 + t] = (float4){0.f, 0.f, 0.f, 0.f};
  }
}

// =====================================================================
// Conv: M=64 flat pos/block (grid 1176), N=128, K=6912.
// Wave decomposition 1x4: each wave = full 64 rows x 32-col quadrant.
// B(wf) loads distinct per wave (block wf L2 traffic ~12 TB/s);
// A ds_reads are bank-optimal at APITCH=72 (8 dw/bank = full LDS BW;
// SQ_LDS_BANK_CONFLICT ~16.5M is the inherent b128 multi-pass count,
// not an inefficiency).  launch_bounds(256,4): (256,8) forces 32 VGPR
// and spills 522 MB — do not raise.
// =====================================================================
#define APITCH 72
static __device__ __forceinline__ void conv_stage(unsigned short* dst,
                                                  const unsigned short* __restrict__ imgP,
                                                  int s, int m0, int t) {
  int lvl = s / 12, r = s - lvl * 12;
  int ck = r / 3, ky = r - ck * 3;
  const unsigned short* base = imgP
      + (size_t)(GUARD + lvl * LVLPOS + m0 - 1 + (ky - 1) * 114) * 256 + ck * 64;
  for (int v = t; v < 528; v += 256) {          // 66 rows x 8 chunks
    int p = v >> 3, seg = v & 7;
    *(uint4*)(dst + p * APITCH + seg * 8) = *(const uint4*)(base + (size_t)p * 256 + seg * 8);
  }
}

static __device__ __forceinline__ void conv_compute(const unsigned short* As_,
                                                    const unsigned short* __restrict__ wf,
                                                    int s, int nh, int m, int kq,
                                                    f32x4 (&acc)[4][2]) {
  // wave nh covers output cols nh*32 .. nh*32+31 (fragment rows nh*4 .. nh*4+3)
  const unsigned short* W0 = wf + (size_t)(3 * s) * 8192 + (nh * 4) * 512 + (m + 16 * kq) * 8;
  #pragma unroll
  for (int kx = 0; kx < 3; ++kx) {
    const unsigned short* Wp = W0 + kx * 8192;
    bf16x8 bv[2][2];
    #pragma unroll
    for (int nt = 0; nt < 2; ++nt) {
      bv[nt][0] = *(const bf16x8*)(Wp + (nt * 2) * 512);
      bv[nt][1] = *(const bf16x8*)(Wp + (nt * 2 + 1) * 512);
    }
    #pragma unroll
    for (int mt = 0; mt < 4; ++mt) {
      const unsigned short* ap = As_ + (mt * 16 + m + kx) * APITCH + kq * 8;
      bf16x8 a0 = *(const bf16x8*)(ap);
      bf16x8 a1 = *(const bf16x8*)(ap + 32);
      #pragma unroll
      for (int nt = 0; nt < 2; ++nt) {
        acc[mt][nt] = __builtin_amdgcn_mfma_f32_16x16x32_bf16(a0, bv[nt][0], acc[mt][nt], 0, 0, 0);
        acc[mt][nt] = __builtin_amdgcn_mfma_f32_16x16x32_bf16(a1, bv[nt][1], acc[mt][nt], 0, 0, 0);
      }
    }
  }
}

__global__ __launch_bounds__(256, 4) void k_conv(const unsigned short* __restrict__ imgP,
                                                 const unsigned short* __restrict__ wf,
                                                 const float* __restrict__ bias,
                                                 unsigned short* __restrict__ fdat) {
  __shared__ unsigned short As[2][66 * APITCH];
  const int t = threadIdx.x, lane = t & 63, wave = t >> 6;
  const int nh = wave;                          // 1x4 decomposition
  const int m = lane & 15, kq = lane >> 4;
  const int m0 = blockIdx.x * 64;

  f32x4 acc[4][2];
  #pragma unroll
  for (int i = 0; i < 4; ++i)
    #pragma unroll
    for (int j = 0; j < 2; ++j) acc[i][j] = (f32x4){0.f, 0.f, 0.f, 0.f};

  conv_stage(As[0], imgP, 0, m0, t);
  #pragma unroll 1
  for (int s = 0; s < 36; s += 2) {
    __syncthreads();
    if (s + 1 < 36) conv_stage(As[1], imgP, s + 1, m0, t);
    conv_compute(As[0], wf, s, nh, m, kq, acc);
    __syncthreads();
    if (s + 2 < 36) conv_stage(As[0], imgP, s + 2, m0, t);
    conv_compute(As[1], wf, s + 1, nh, m, kq, acc);
  }
  __syncthreads();

  // epilogue: bias + bf16, LDS repack (overlays As), contiguous store
  unsigned short* Ep = &As[0][0];               // [64][128] = 16384 B <= 19008
  #pragma unroll
  for (int nt = 0; nt < 2; ++nt) {
    int oc = nh * 32 + nt * 16 + m;
    float bb = bias[oc];
    #pragma unroll
    for (int mt = 0; mt < 4; ++mt)
      #pragma unroll
      for (int rr = 0; rr < 4; ++rr)
        Ep[(mt * 16 + kq * 4 + rr) * 128 + oc] = f2bf(acc[mt][nt][rr] + bb);
  }
  __syncthreads();
  unsigned short* dst = fdat + (size_t)m0 * 128;
  for (int v = t; v < 1024; v += 256)
    *(uint4*)(dst + v * 8) = *(const uint4*)(Ep + v * 8);
}

// =====================================================================
// gather (blocks 0..8191) + pts GEMM (blocks 8192..10239, 64-row tiles),
// stats fused.  LDS union 19456 B.  NPART=64 partials: gather's 2.1M
// global f32 atomics spread over 64x512 addresses (was 16x512 -> 4x
// less per-address serialization).
// =====================================================================
__global__ __launch_bounds__(256) void k_gp(const float* __restrict__ pts_xyz,
                                            const int* __restrict__ cam_ids,
                                            const float* __restrict__ Tm,
                                            const float* __restrict__ Km,
                                            const unsigned short* __restrict__ fdat,
                                            const float* __restrict__ pts_feats,
                                            const unsigned short* __restrict__ pts_wb,
                                            unsigned short* __restrict__ img_raw,
                                            unsigned short* __restrict__ pts_raw,
                                            float* __restrict__ statsP) {
  __shared__ __align__(16) char smem[19456];
  const int t = threadIdx.x, lane = t & 63, wave = t >> 6;

  if (blockIdx.x < 8192) {
    // ---------------- gather + img stats ----------------
    float* sb = (float*)smem;                   // [128] col sums
    float* qb = sb + 128;                       // [128] col sumsq
    if (t < 128) { sb[t] = 0.f; sb[128 + t] = 0.f; }
    __syncthreads();
    const int p0 = blockIdx.x * 16 + wave * 4;
    const uint32_t* fq = (const uint32_t*)fdat;
    float s0 = 0.f, q0 = 0.f, s1 = 0.f, q1 = 0.f;
    #pragma unroll 2
    for (int j = 0; j < 4; ++j) {
      const int p = p0 + j;
      const int b = p >> 16;
      const int cam = cam_ids[p];
      const float X = pts_xyz[(size_t)p * 3], Y = pts_xyz[(size_t)p * 3 + 1], Z = pts_xyz[(size_t)p * 3 + 2];
      const float* Tc = Tm + cam * 16;
      float pcx = Tc[0] * X + Tc[1] * Y + Tc[2]  * Z + Tc[3];
      float pcy = Tc[4] * X + Tc[5] * Y + Tc[6]  * Z + Tc[7];
      float pcz = Tc[8] * X + Tc[9] * Y + Tc[10] * Z + Tc[11];
      const float* Kc = Km + cam * 9;
      float pimx = Kc[0] * 0.125f * pcx + Kc[1] * pcy          + Kc[2] * 0.125f * pcz;
      float pimy = Kc[3] * pcx          + Kc[4] * 0.125f * pcy + Kc[5] * 0.125f * pcz;
      float pimz = Kc[6] * pcx          + Kc[7] * pcy          + Kc[8] * pcz;
      float u = pimx / pimz, vv = pimy / pimz;
      float px = (u / 112.f) * 111.f;
      float py = (vv / 64.f) * 63.f;
      float x0 = floorf(px), y0 = floorf(py);
      float wx = px - x0, wy = py - y0;
      float cxf[4] = {x0, x0 + 1.f, x0, x0 + 1.f};
      float cyf[4] = {y0, y0, y0 + 1.f, y0 + 1.f};
      float cwt[4] = {(1.f - wx) * (1.f - wy), wx * (1.f - wy), (1.f - wx) * wy, wx * wy};
      const int nimg = b * 5 + cam;
      float wv[4]; int idx[4]; bool any = false;
      #pragma unroll
      for (int c4 = 0; c4 < 4; ++c4) {
        float xf = cxf[c4], yf = cyf[c4];
        bool valid = (xf >= 0.f) && (xf <= 111.f) && (yf >= 0.f) && (yf <= 63.f);
        float w = cwt[c4] * (valid ? 1.f : 0.f);
        int xi = (int)fminf(fmaxf(xf, 0.f), 111.f);
        int yi = (int)fminf(fmaxf(yf, 0.f), 63.f);
        wv[c4] = w;
        idx[c4] = (nimg * 66 + yi + 1) * 114 + xi + 1;
        any = any || (w != 0.f);
      }
      float a0 = 0.f, a1 = 0.f;
      if (any) {
        #pragma unroll
        for (int c4 = 0; c4 < 4; ++c4) {
          uint32_t d = fq[(size_t)idx[c4] * 64 + lane];
          a0 = fmaf(wv[c4], bflo(d), a0);
          a1 = fmaf(wv[c4], bfhi(d), a1);
        }
      }
      s0 += a0; q0 += a0 * a0; s1 += a1; q1 += a1 * a1;
      ((uint32_t*)img_raw)[(size_t)p * 64 + lane] =
          (uint32_t)f2bf(a0) | ((uint32_t)f2bf(a1) << 16);
    }
    atomicAdd(&sb[lane * 2], s0);
    atomicAdd(&sb[lane * 2 + 1], s1);
    atomicAdd(&qb[lane * 2], q0);
    atomicAdd(&qb[lane * 2 + 1], q1);
    __syncthreads();
    if (t < 128) {
      float* sp = statsP + (size_t)(blockIdx.x & (NPART - 1)) * 512;
      atomicAdd(sp + t, sb[t]);
      atomicAdd(sp + 128 + t, qb[t]);
    }
  } else {
    // ---------------- pts GEMM (64-row tile) + pts stats ----------------
    const int pb = blockIdx.x - 8192;                // 0..2047
    const size_t r0 = (size_t)pb * 64;
    unsigned short* As2 = (unsigned short*)smem;     // [64][136] = 17408 B
    const int mh = wave & 1, nh = wave >> 1;
    const int m = lane & 15, kq = lane >> 4;
    for (int v = t; v < 2048; v += 256) {
      int mm = v >> 5, seg = v & 31;
      float4 f = *(const float4*)(pts_feats + (r0 + mm) * 128 + seg * 4);
      uint2 d;
      d.x = (uint32_t)f2bf(f.x) | ((uint32_t)f2bf(f.y) << 16);
      d.y = (uint32_t)f2bf(f.z) | ((uint32_t)f2bf(f.w) << 16);
      *(uint2*)(As2 + mm * 136 + seg * 4) = d;
    }
    __syncthreads();
    f32x4 acc[2][4];
    #pragma unroll
    for (int i = 0; i < 2; ++i)
      #pragma unroll
      for (int jj = 0; jj < 4; ++jj) acc[i][jj] = (f32x4){0.f, 0.f, 0.f, 0.f};
    #pragma unroll
    for (int ks = 0; ks < 4; ++ks) {
      bf16x8 af0 = *(const bf16x8*)(As2 + (mh * 32 + 0 * 16 + m) * 136 + ks * 32 + kq * 8);
      bf16x8 af1 = *(const bf16x8*)(As2 + (mh * 32 + 1 * 16 + m) * 136 + ks * 32 + kq * 8);
      #pragma unroll
      for (int nt = 0; nt < 4; ++nt) {
        bf16x8 bv = *(const bf16x8*)(pts_wb + (size_t)((ks * 8 + nh * 4 + nt) * 512) + lane * 8);
        acc[0][nt] = __builtin_amdgcn_mfma_f32_16x16x32_bf16(af0, bv, acc[0][nt], 0, 0, 0);
        acc[1][nt] = __builtin_amdgcn_mfma_f32_16x16x32_bf16(af1, bv, acc[1][nt], 0, 0, 0);
      }
    }
    __syncthreads();
    #pragma unroll
    for (int mt = 0; mt < 2; ++mt)
      #pragma unroll
      for (int nt = 0; nt < 4; ++nt)
        #pragma unroll
        for (int rr = 0; rr < 4; ++rr)
          As2[(mh * 32 + mt * 16 + kq * 4 + rr) * 128 + nh * 64 + nt * 16 + m] = f2bf(acc[mt][nt][rr]);
    __syncthreads();
    unsigned short* dst = pts_raw + r0 * 128;
    for (int v = t; v < 1024; v += 256)
      *(uint4*)(dst + v * 8) = *(const uint4*)(As2 + v * 8);
    // column stats from repacked tile
    float* ps = (float*)(smem + 17408);              // [256] sums
    float* pq = (float*)(smem + 18432);              // [256] sumsq
    {
      int col = t & 127, rh = t >> 7;
      float s = 0.f, q = 0.f;
      for (int i = 0; i < 32; ++i) {
        float v = __uint_as_float((uint32_t)As2[(rh * 32 + i) * 128 + col] << 16);
        s += v; q += v * v;
      }
      ps[rh * 128 + col] = s;
      pq[rh * 128 + col] = q;
    }
    __syncthreads();
    if (t < 128) {
      float* sp = statsP + (size_t)(blockIdx.x & (NPART - 1)) * 512;
      atomicAdd(sp + 256 + t, ps[t] + ps[128 + t]);
      atomicAdd(sp + 384 + t, pq[t] + pq[128 + t]);
    }
  }
}

// =====================================================================
// finalize: reduce statsP, out = relu(a_img*img + a_pts*pts + c), fp32
// uint2 loads (8B/lane) + float4 stores (16B/lane)
// =====================================================================
__global__ __launch_bounds__(256) void k_final(const unsigned short* __restrict__ img_raw,
                                               const unsigned short* __restrict__ pts_raw,
                                               const float* __restrict__ statsP,
                                               const float* __restrict__ img_gamma,
                                               const float* __restrict__ img_beta,
                                               const float* __restrict__ pts_gamma,
                                               const float* __restrict__ pts_beta,
                                               float* __restrict__ out) {
  __shared__ float sA[128], sB[128], sC[128];
  const int t = threadIdx.x;
  if (t < 128) {
    float si = 0.f, qi = 0.f, sp = 0.f, qp = 0.f;
    for (int k = 0; k < NPART; ++k) {
      const float* st = statsP + (size_t)k * 512;
      si += st[t]; qi += st[128 + t]; sp += st[256 + t]; qp += st[384 + t];
    }
    const float Nr = 131072.f;
    float mu_i = si / Nr;
    float var_i = qi / Nr - mu_i * mu_i;
    float a_i = img_gamma[t] * rsqrtf(var_i + 1e-3f);
    float mu_p = sp / Nr;
    float var_p = qp / Nr - mu_p * mu_p;
    float a_p = pts_gamma[t] * rsqrtf(var_p + 1e-3f);
    sA[t] = a_i; sB[t] = a_p;
    sC[t] = img_beta[t] + pts_beta[t] - a_i * mu_i - a_p * mu_p;
  }
  __syncthreads();
  const uint32_t* ir = (const uint32_t*)img_raw;
  const uint32_t* pr = (const uint32_t*)pts_raw;
  size_t g0 = (size_t)blockIdx.x * 2048;
  #pragma unroll
  for (int i = 0; i < 4; ++i) {
    size_t g = g0 + (size_t)i * 512 + t * 2;    // even; this thread covers g, g+1
    uint2 di = *(const uint2*)(ir + g);
    uint2 dp = *(const uint2*)(pr + g);
    int c = (int)(g & 63) * 2;                  // channels c..c+3
    float4 o;
    o.x = fmaxf(0.f, sA[c]     * bflo(di.x) + sB[c]     * bflo(dp.x) + sC[c]);
    o.y = fmaxf(0.f, sA[c + 1] * bfhi(di.x) + sB[c + 1] * bfhi(dp.x) + sC[c + 1]);
    o.z = fmaxf(0.f, sA[c + 2] * bflo(di.y) + sB[c + 2] * bflo(dp.y) + sC[c + 2]);
    o.w = fmaxf(0.f, sA[c + 3] * bfhi(di.y) + sB[c + 3] * bfhi(dp.y) + sC[c + 3]);
    *(float4*)(out + g * 2) = o;
  }
}

// =====================================================================
extern "C" void kernel_launch(void* const* d_in, const int* in_sizes, int n_in,
                              void* d_out, int out_size, void* d_ws, size_t ws_size,
                              hipStream_t stream) {
  const float* img_feats = (const float*)d_in[0];
  const float* pts_xyz   = (const float*)d_in[1];
  const float* pts_feats = (const float*)d_in[2];
  const float* Tm        = (const float*)d_in[3];
  const float* Km        = (const float*)d_in[4];
  const float* conv_w    = (const float*)d_in[5];
  const float* conv_b    = (const float*)d_in[6];
  const float* img_w     = (const float*)d_in[7];
  // d_in[8] img_b, d_in[12] pts_b cancel under BN mean subtraction
  const float* img_gamma = (const float*)d_in[9];
  const float* img_beta  = (const float*)d_in[10];
  const float* pts_w     = (const float*)d_in[11];
  const float* pts_gamma = (const float*)d_in[13];
  const float* pts_beta  = (const float*)d_in[14];
  const int*   cam_ids   = (const int*)d_in[15];

  char* wsb = (char*)d_ws;
  unsigned short* wf      = (unsigned short*)(wsb + OFF_WF);
  float*          bias    = (float*)(wsb + OFF_BIAS);
  unsigned short* pts_wb  = (unsigned short*)(wsb + OFF_PTSWB);
  float*          statsP  = (float*)(wsb + OFF_STATSP);
  unsigned short* fdat    = (unsigned short*)(wsb + OFF_FDAT);
  unsigned short* imgP    = (unsigned short*)(wsb + OFF_IMGP);
  unsigned short* img_raw = (unsigned short*)(wsb + OFF_IRAW);
  unsigned short* pts_raw = (unsigned short*)(wsb + OFF_PRAW);

  k_pre<<<dim3(2511), dim3(256), 0, stream>>>(img_feats, img_w, conv_w, conv_b, pts_w,
                                              wf, bias, pts_wb, imgP, statsP);
  k_conv<<<dim3(1176), dim3(256), 0, stream>>>(imgP, wf, bias, fdat);
  k_gp<<<dim3(10240), dim3(256), 0, stream>>>(pts_xyz, cam_ids, Tm, Km, fdat,
                                              pts_feats, pts_wb, img_raw, pts_raw, statsP);
  k_final<<<dim3(4096), dim3(256), 0, stream>>>(img_raw, pts_raw, statsP,
                                                img_gamma, img_beta, pts_gamma, pts_beta,
                                                (float*)d_out);
}